// Round 3
// baseline (495.801 us; speedup 1.0000x reference)
//
#include <hip/hip_runtime.h>

// SoftmaxMatcher on MI355X — round 3.
// Changes vs R2:
//  * prep_tgt: raw bf16 hi/lo split (normalization folded into per-pixel invx,
//    applied post-MFMA via linearity of the dot product) -> low VGPR, BW-bound.
//  * k_gemm: 512 threads / 8 waves on 128x128 tile -> 4 waves/SIMD occupancy.
//  * grid ny-fastest so 4 blocks sharing a B-tile are temporally adjacent;
//    nontemporal osm stores to protect B in L3.

typedef short  v8s __attribute__((ext_vector_type(8)));
typedef unsigned short v8u __attribute__((ext_vector_type(8)));
typedef float  v4f __attribute__((ext_vector_type(4)));

#define EXP2_SCALE 144.269504088896f   // 1/(0.01*ln2)

// ---- workspace layout (bytes) ----
static const size_t O_AHI  = 0;                        // ushort[2048*128]
static const size_t O_ALO  = O_AHI  + 262144ull*2;
static const size_t O_SRCN = O_ALO  + 262144ull*2;     // float[2048*128]
static const size_t O_BHI  = O_SRCN + 262144ull*4;     // ushort[262144*128] 64MB
static const size_t O_BLO  = O_BHI  + 33554432ull*2;   // 64MB
static const size_t O_PART = O_BLO  + 33554432ull*2;   // float2[2048*512]   8MB
static const size_t O_ROWS = O_PART + 2048ull*512*8;   // float4[2048]
static const size_t O_INVX = O_ROWS + 2048ull*16;      // float[262144]      1MB

static __device__ inline unsigned short f2bf(float x) {
    unsigned u = __float_as_uint(x);
    u = u + 0x7FFFu + ((u >> 16) & 1u);   // RNE
    return (unsigned short)(u >> 16);
}
static __device__ inline float bf2f(unsigned short h) {
    return __uint_as_float(((unsigned)h) << 16);
}

__device__ __forceinline__ void gl_lds16(const void* g, void* l) {
    auto gp = (const __attribute__((address_space(1))) unsigned int*)(uintptr_t)g;
    auto lp = (__attribute__((address_space(3))) unsigned int*)(uintptr_t)l;
    __builtin_amdgcn_global_load_lds(gp, lp, 16, 0, 0);
}

// ---------------- prep: normalize src keypoint descs, bf16 hi/lo, [row][k] ----
__global__ void __launch_bounds__(256) k_prep_src(const float* __restrict__ kd,
                                                  float* __restrict__ srcN,
                                                  unsigned short* __restrict__ Ahi,
                                                  unsigned short* __restrict__ Alo) {
    int gw = blockIdx.x * 4 + (threadIdx.x >> 6);  // 0..2047 = b*512+n
    int l  = threadIdx.x & 63;
    int b  = gw >> 9, n = gw & 511;
    const float* base = kd + (size_t)(2 * b) * 128 * 512;
    float x0 = base[l * 512 + n];
    float x1 = base[(l + 64) * 512 + n];
    float ss = x0 * x0 + x1 * x1;
#pragma unroll
    for (int m = 1; m < 64; m <<= 1) ss += __shfl_xor(ss, m, 64);
    float inv = 1.0f / fmaxf(sqrtf(ss), 1e-12f);
    float xn0 = x0 * inv, xn1 = x1 * inv;
    int ob = gw * 128;
    srcN[ob + l] = xn0;  srcN[ob + l + 64] = xn1;
    unsigned short h0 = f2bf(xn0), h1 = f2bf(xn1);
    Ahi[ob + l] = h0;        Ahi[ob + l + 64] = h1;
    Alo[ob + l] = f2bf(xn0 - bf2f(h0));
    Alo[ob + l + 64] = f2bf(xn1 - bf2f(h1));
}

// ---------------- prep: RAW tgt split to [m][k] hi/lo + per-pixel inv-norm ----
__global__ void __launch_bounds__(256) k_prep_tgt(const float* __restrict__ dd,
                                                  unsigned short* __restrict__ Bhi,
                                                  unsigned short* __restrict__ Blo,
                                                  float* __restrict__ invx) {
    int t = blockIdx.x * 256 + threadIdx.x;   // 0..262143 = b*65536 + p
    int b = t >> 16;
    int p = t & 65535;
    const float* src = dd + (size_t)(2 * b + 1) * 128 * 65536 + p;
    float ss = 0.f;
    size_t ob = (size_t)t * 128;
#pragma unroll 4
    for (int c8 = 0; c8 < 16; ++c8) {
        v8u h8, l8;
#pragma unroll
        for (int j = 0; j < 8; ++j) {
            float x = src[(size_t)(c8 * 8 + j) * 65536];
            ss += x * x;
            unsigned short h = f2bf(x);
            h8[j] = h;
            l8[j] = f2bf(x - bf2f(h));
        }
        *(v8u*)(Bhi + ob + c8 * 8) = h8;
        *(v8u*)(Blo + ob + c8 * 8) = l8;
    }
    invx[t] = 1.0f / fmaxf(sqrtf(ss), 1e-12f);
}

// ---------------- fused GEMM (128x128 tile, K_ext=384, LDS staged) ----------
// MODE 0: per-(row, mtile) partials {sum e, sum e*m_local}
// MODE 1: write p = e * invS[row] to soft_match_vals
// grid (4 ny, 512 mt, 4 b), 512 threads = 8 waves (wm = w>>1 m-quarter(32),
// wn = w&1 n-half(64)); s = acc*invx[m]; e = exp2((s-1)*144.27)
template <int MODE>
__global__ void __launch_bounds__(512, 2) k_gemm(const unsigned short* __restrict__ Ahi,
                                                 const unsigned short* __restrict__ Alo,
                                                 const unsigned short* __restrict__ Bhi,
                                                 const unsigned short* __restrict__ Blo,
                                                 const float* __restrict__ invx,
                                                 const float4* __restrict__ rows,
                                                 float2* __restrict__ part,
                                                 float* __restrict__ osm) {
    __shared__ v4f ldsbuf[4096];           // 64 KB: 2 x (Kp 16K + Px 16K); aliased by epilogues
    __shared__ float ldsInv[128];
    char* lds = (char*)ldsbuf;

    const int tid = threadIdx.x;
    const int l = tid & 63, w = tid >> 6;
    const int wm = w >> 1, wn = w & 1;
    const int l15 = l & 15, l16 = l >> 4;
    const int ny = blockIdx.x, mt = blockIdx.y, b = blockIdx.z;

    const size_t kprow0 = (size_t)(b * 512 + ny * 128) * 128;   // Ahi/Alo elem offset
    const size_t pxrow0 = (size_t)(b * 65536 + mt * 128) * 128; // Bhi/Blo elem offset

    if (tid < 128) ldsInv[tid] = invx[b * 65536 + mt * 128 + tid];

    // staging: 1024 granules (16B) per matrix tile, 2 per thread
    int soff[2], sdst[2];
#pragma unroll
    for (int i = 0; i < 2; ++i) {
        int s = tid + i * 512;
        int rl = s >> 3, g = s & 7;
        soff[i] = rl * 128 + ((g ^ (rl & 7)) << 3);   // pre-swizzled global elem offset
        sdst[i] = s << 4;                             // linear LDS byte offset
    }

    v4f acc[2][4];
#pragma unroll
    for (int mf = 0; mf < 2; ++mf)
#pragma unroll
        for (int nf = 0; nf < 4; ++nf) { v4f z = {0.f, 0.f, 0.f, 0.f}; acc[mf][nf] = z; }

    // K-step kb: term t=kb>>1 -> {Ah*Bh, Ah*Bl, Al*Bh}; k_off=(kb&1)*64
#define STAGE(kb, buf)                                                              \
    {                                                                               \
        const unsigned short* kp = (((kb) < 4) ? Ahi : Alo) + kprow0 + (((kb) & 1) << 6); \
        const unsigned short* px = ((((kb) >> 1) == 1) ? Blo : Bhi) + pxrow0 + (((kb) & 1) << 6); \
        char* base = lds + (buf) * 32768;                                           \
        _Pragma("unroll")                                                           \
        for (int i = 0; i < 2; ++i) {                                               \
            gl_lds16(kp + soff[i], base + sdst[i]);                                 \
            gl_lds16(px + soff[i], base + 16384 + sdst[i]);                         \
        }                                                                           \
    }

    STAGE(0, 0);
    __syncthreads();
    int buf = 0;
    for (int kb = 0; kb < 6; ++kb) {
        if (kb < 5) STAGE(kb + 1, buf ^ 1);
        const char* kp = lds + buf * 32768;
        const char* px = kp + 16384;
#pragma unroll
        for (int ks = 0; ks < 2; ++ks) {
            v8s af[2], bf[4];
#pragma unroll
            for (int mf = 0; mf < 2; ++mf) {
                int r = wm * 32 + mf * 16 + l15;
                int g = ((ks << 2) | l16) ^ (r & 7);
                af[mf] = *(const v8s*)(px + r * 128 + (g << 4));
            }
#pragma unroll
            for (int nf = 0; nf < 4; ++nf) {
                int r = wn * 64 + nf * 16 + l15;
                int g = ((ks << 2) | l16) ^ (r & 7);
                bf[nf] = *(const v8s*)(kp + r * 128 + (g << 4));
            }
#pragma unroll
            for (int mf = 0; mf < 2; ++mf)
#pragma unroll
                for (int nf = 0; nf < 4; ++nf)
                    acc[mf][nf] = __builtin_amdgcn_mfma_f32_16x16x32_bf16(af[mf], bf[nf], acc[mf][nf], 0, 0, 0);
        }
        __syncthreads();
        buf ^= 1;
    }
#undef STAGE
    // output frag: row = m = wm*32+mf*16+l16*4+r; col = n = wn*64+nf*16+l15

    if (MODE == 0) {
        float sS[4], sM[4];
#pragma unroll
        for (int nf = 0; nf < 4; ++nf) { sS[nf] = 0.f; sM[nf] = 0.f; }
#pragma unroll
        for (int mf = 0; mf < 2; ++mf) {
            int mloc = wm * 32 + mf * 16 + l16 * 4;
#pragma unroll
            for (int nf = 0; nf < 4; ++nf)
#pragma unroll
                for (int r = 0; r < 4; ++r) {
                    float sv = acc[mf][nf][r] * ldsInv[mloc + r];
                    float e = __builtin_amdgcn_exp2f(fmaf(sv, EXP2_SCALE, -EXP2_SCALE));
                    sS[nf] += e;
                    sM[nf] = fmaf(e, (float)(mloc + r), sM[nf]);
                }
        }
#pragma unroll
        for (int nf = 0; nf < 4; ++nf) {   // reduce across l16 groups (m)
            sS[nf] += __shfl_xor(sS[nf], 16, 64); sS[nf] += __shfl_xor(sS[nf], 32, 64);
            sM[nf] += __shfl_xor(sM[nf], 16, 64); sM[nf] += __shfl_xor(sM[nf], 32, 64);
        }
        float* red = (float*)lds;          // [8 w][4 nf][16 l15][2]
        if (l < 16) {
#pragma unroll
            for (int nf = 0; nf < 4; ++nf) {
                red[((w * 4 + nf) * 16 + l15) * 2 + 0] = sS[nf];
                red[((w * 4 + nf) * 16 + l15) * 2 + 1] = sM[nf];
            }
        }
        __syncthreads();
        // combine wm quarters: 256 thr = wn(2) x nf(4) x l15(16) x q(2)
        if (tid < 256) {
            int q = tid & 1, p15 = (tid >> 1) & 15, pnf = (tid >> 5) & 3, pwn = (tid >> 7) & 1;
            float vs = 0.f;
#pragma unroll
            for (int pwm = 0; pwm < 4; ++pwm)
                vs += red[(((pwm * 2 + pwn) * 4 + pnf) * 16 + p15) * 2 + q];
            int rowg = b * 512 + ny * 128 + pwn * 64 + pnf * 16 + p15;
            ((float*)part)[((size_t)rowg * 512 + mt) * 2 + q] = vs;
        }
    } else {
        float invs[4];
#pragma unroll
        for (int nf = 0; nf < 4; ++nf)
            invs[nf] = rows[b * 512 + ny * 128 + wn * 64 + nf * 16 + l15].x;
        // write p tile into LDS [128 n][128 m] f32, granule-swizzled
#pragma unroll
        for (int mf = 0; mf < 2; ++mf) {
            int mloc = wm * 32 + mf * 16 + l16 * 4;
#pragma unroll
            for (int nf = 0; nf < 4; ++nf) {
                int nloc = wn * 64 + nf * 16 + l15;
                v4f pv;
#pragma unroll
                for (int r = 0; r < 4; ++r) {
                    float sv = acc[mf][nf][r] * ldsInv[mloc + r];
                    pv[r] = __builtin_amdgcn_exp2f(fmaf(sv, EXP2_SCALE, -EXP2_SCALE)) * invs[nf];
                }
                int g = (mloc >> 2) ^ (nloc & 7);
                *(v4f*)(lds + nloc * 512 + (g << 4)) = pv;
            }
        }
        __syncthreads();
        // cooperative store: 512B contiguous per row, nontemporal (protect L3)
        size_t obase = (size_t)(b * 512 + ny * 128) * 65536 + (size_t)mt * 128;
        int g = tid & 31, rh = tid >> 5;   // rh 0..15
#pragma unroll
        for (int it = 0; it < 8; ++it) {
            int r = it * 16 + rh;
            v4f v = *(const v4f*)(lds + r * 512 + ((g ^ (r & 7)) << 4));
            __builtin_nontemporal_store(v, (v4f*)(osm + obase + (size_t)r * 65536 + (g << 2)));
        }
    }
}

// ---------------- reduce partials -> rowstats{invS,u,v}; write pseudo_coords ----
__global__ void __launch_bounds__(256) k_reduce(const float2* __restrict__ part,
                                                float4* __restrict__ rows,
                                                float* __restrict__ out) {
    int r = blockIdx.x * 4 + (threadIdx.x >> 6);  // 0..2047
    int l = threadIdx.x & 63;
    float S = 0.f, Su = 0.f, Sv = 0.f;
#pragma unroll
    for (int i = 0; i < 8; ++i) {
        int mtv = l + i * 64;
        float2 p = part[(size_t)r * 512 + mtv];
        S += p.x;
        Su += (float)((mtv & 1) * 128) * p.x + p.y;
        Sv += (float)(mtv >> 1) * p.x;
    }
#pragma unroll
    for (int m = 1; m < 64; m <<= 1) {
        S += __shfl_xor(S, m, 64);
        Su += __shfl_xor(Su, m, 64);
        Sv += __shfl_xor(Sv, m, 64);
    }
    if (l == 0) {
        float invS = 1.0f / S;
        float u = Su * invS, v = Sv * invS;
        rows[r] = make_float4(invS, u, v, 0.f);
        out[r * 2] = u;
        out[r * 2 + 1] = v;
    }
}

// ---------------- bilinear sample + match weights ----
__global__ void __launch_bounds__(256) k_sample(const float* __restrict__ ksc,
                                                const float* __restrict__ sd,
                                                const float* __restrict__ dd,
                                                const float* __restrict__ srcN,
                                                const float4* __restrict__ rows,
                                                float* __restrict__ out) {
    int gw = blockIdx.x * 4 + (threadIdx.x >> 6);  // b*512+n
    int l = threadIdx.x & 63;
    int b = gw >> 9, n = gw & 511;
    float4 rs = rows[gw];
    float u = rs.y, v = rs.z;
    float un = 2.0f * u / 255.0f - 1.0f;
    float vn = 2.0f * v / 255.0f - 1.0f;
    float x = ((un + 1.0f) * 256.0f - 1.0f) * 0.5f;
    float y = ((vn + 1.0f) * 256.0f - 1.0f) * 0.5f;
    float x0f = floorf(x), y0f = floorf(y);
    int x0 = (int)x0f, y0 = (int)y0f;
    int x1 = x0 + 1, y1 = y0 + 1;
    float wx1 = x - x0f, wy1 = y - y0f;
    float wx0 = 1.0f - wx1, wy0 = 1.0f - wy1;
    float m00 = ((x0 >= 0) & (x0 <= 255) & (y0 >= 0) & (y0 <= 255)) ? 1.f : 0.f;
    float m10 = ((x1 >= 0) & (x1 <= 255) & (y0 >= 0) & (y0 <= 255)) ? 1.f : 0.f;
    float m01 = ((x0 >= 0) & (x0 <= 255) & (y1 >= 0) & (y1 <= 255)) ? 1.f : 0.f;
    float m11 = ((x1 >= 0) & (x1 <= 255) & (y1 >= 0) & (y1 <= 255)) ? 1.f : 0.f;
    int cx0 = min(max(x0, 0), 255), cx1 = min(max(x1, 0), 255);
    int cy0 = min(max(y0, 0), 255), cy1 = min(max(y1, 0), 255);
    int i00 = cy0 * 256 + cx0, i10 = cy0 * 256 + cx1;
    int i01 = cy1 * 256 + cx0, i11 = cy1 * 256 + cx1;
    float w00 = wx0 * wy0 * m00, w10 = wx1 * wy0 * m10;
    float w01 = wx0 * wy1 * m01, w11 = wx1 * wy1 * m11;

    const float* sdb = sd + (size_t)(2 * b + 1) * 65536;
    float ps = w00 * sdb[i00] + w10 * sdb[i10] + w01 * sdb[i01] + w11 * sdb[i11];

    const float* ddb = dd + (size_t)(2 * b + 1) * 128 * 65536;
    float dot = 0.f;
#pragma unroll
    for (int h = 0; h < 2; ++h) {
        int c = l + h * 64;
        const float* dc = ddb + (size_t)c * 65536;
        float pd = w00 * dc[i00] + w10 * dc[i10] + w01 * dc[i01] + w11 * dc[i11];
        dot += srcN[gw * 128 + c] * pd;
    }
#pragma unroll
    for (int m = 1; m < 64; m <<= 1) dot += __shfl_xor(dot, m, 64);
    if (l == 0) {
        float dms = dot / 128.0f;
        float sscore = ksc[(2 * b) * 512 + n];
        out[4096 + gw] = 0.5f * (dms + 1.0f) * sscore * ps;
    }
}

extern "C" void kernel_launch(void* const* d_in, const int* in_sizes, int n_in,
                              void* d_out, int out_size, void* d_ws, size_t ws_size,
                              hipStream_t stream) {
    const float* ksc = (const float*)d_in[0];  // (8,1,512)
    const float* kd  = (const float*)d_in[1];  // (8,128,512)
    const float* sd  = (const float*)d_in[2];  // (8,1,256,256)
    const float* dd  = (const float*)d_in[3];  // (8,128,256,256)
    float* out = (float*)d_out;                // coords(4096) | mw(2048) | sm(134217728)
    char* ws = (char*)d_ws;

    unsigned short* Ahi  = (unsigned short*)(ws + O_AHI);
    unsigned short* Alo  = (unsigned short*)(ws + O_ALO);
    float*          srcN = (float*)(ws + O_SRCN);
    unsigned short* Bhi  = (unsigned short*)(ws + O_BHI);
    unsigned short* Blo  = (unsigned short*)(ws + O_BLO);
    float2*         part = (float2*)(ws + O_PART);
    float4*         rows = (float4*)(ws + O_ROWS);
    float*          invx = (float*)(ws + O_INVX);
    float*          osm  = out + 6144;

    k_prep_src<<<512, 256, 0, stream>>>(kd, srcN, Ahi, Alo);
    k_prep_tgt<<<1024, 256, 0, stream>>>(dd, Bhi, Blo, invx);
    k_gemm<0><<<dim3(4, 512, 4), 512, 0, stream>>>(Ahi, Alo, Bhi, Blo, invx, rows, part, osm);
    k_reduce<<<512, 256, 0, stream>>>(part, rows, out);
    k_gemm<1><<<dim3(4, 512, 4), 512, 0, stream>>>(Ahi, Alo, Bhi, Blo, invx, rows, part, osm);
    k_sample<<<512, 256, 0, stream>>>(ksc, sd, dd, srcN, rows, out);
}

// Round 4
// 474.741 us; speedup vs baseline: 1.0444x; 1.0444x over previous
//
#include <hip/hip_runtime.h>

// SoftmaxMatcher on MI355X — round 4.
// = R2's 4-wave 128x128 2-barrier GEMM structure (faster than R3's 8-wave)
//   + T4 counted-vmcnt double-buffer loop (raw s_barrier, never drain vmcnt
//     to 0 mid-loop) so next-tile global_load_lds stays in flight across
//     the barrier instead of being drained by __syncthreads.
//   + R3's low-VGPR prep_tgt (raw bf16 split, invx folded in post-MFMA).

typedef short  v8s __attribute__((ext_vector_type(8)));
typedef unsigned short v8u __attribute__((ext_vector_type(8)));
typedef float  v4f __attribute__((ext_vector_type(4)));

#define EXP2_SCALE 144.269504088896f   // 1/(0.01*ln2)

// ---- workspace layout (bytes) ----
static const size_t O_AHI  = 0;                        // ushort[2048*128]
static const size_t O_ALO  = O_AHI  + 262144ull*2;
static const size_t O_SRCN = O_ALO  + 262144ull*2;     // float[2048*128]
static const size_t O_BHI  = O_SRCN + 262144ull*4;     // ushort[262144*128] 64MB
static const size_t O_BLO  = O_BHI  + 33554432ull*2;   // 64MB
static const size_t O_PART = O_BLO  + 33554432ull*2;   // float2[2048*512]   8MB
static const size_t O_ROWS = O_PART + 2048ull*512*8;   // float4[2048]
static const size_t O_INVX = O_ROWS + 2048ull*16;      // float[262144]      1MB

static __device__ inline unsigned short f2bf(float x) {
    unsigned u = __float_as_uint(x);
    u = u + 0x7FFFu + ((u >> 16) & 1u);   // RNE
    return (unsigned short)(u >> 16);
}
static __device__ inline float bf2f(unsigned short h) {
    return __uint_as_float(((unsigned)h) << 16);
}

__device__ __forceinline__ void gl_lds16(const void* g, void* l) {
    auto gp = (const __attribute__((address_space(1))) unsigned int*)(uintptr_t)g;
    auto lp = (__attribute__((address_space(3))) unsigned int*)(uintptr_t)l;
    __builtin_amdgcn_global_load_lds(gp, lp, 16, 0, 0);
}

// ---------------- prep: normalize src keypoint descs, bf16 hi/lo, [row][k] ----
__global__ void __launch_bounds__(256) k_prep_src(const float* __restrict__ kd,
                                                  float* __restrict__ srcN,
                                                  unsigned short* __restrict__ Ahi,
                                                  unsigned short* __restrict__ Alo) {
    int gw = blockIdx.x * 4 + (threadIdx.x >> 6);  // 0..2047 = b*512+n
    int l  = threadIdx.x & 63;
    int b  = gw >> 9, n = gw & 511;
    const float* base = kd + (size_t)(2 * b) * 128 * 512;
    float x0 = base[l * 512 + n];
    float x1 = base[(l + 64) * 512 + n];
    float ss = x0 * x0 + x1 * x1;
#pragma unroll
    for (int m = 1; m < 64; m <<= 1) ss += __shfl_xor(ss, m, 64);
    float inv = 1.0f / fmaxf(sqrtf(ss), 1e-12f);
    float xn0 = x0 * inv, xn1 = x1 * inv;
    int ob = gw * 128;
    srcN[ob + l] = xn0;  srcN[ob + l + 64] = xn1;
    unsigned short h0 = f2bf(xn0), h1 = f2bf(xn1);
    Ahi[ob + l] = h0;        Ahi[ob + l + 64] = h1;
    Alo[ob + l] = f2bf(xn0 - bf2f(h0));
    Alo[ob + l + 64] = f2bf(xn1 - bf2f(h1));
}

// ---------------- prep: RAW tgt split to [m][k] hi/lo + per-pixel inv-norm ----
__global__ void __launch_bounds__(256) k_prep_tgt(const float* __restrict__ dd,
                                                  unsigned short* __restrict__ Bhi,
                                                  unsigned short* __restrict__ Blo,
                                                  float* __restrict__ invx) {
    int t = blockIdx.x * 256 + threadIdx.x;   // 0..262143 = b*65536 + p
    int b = t >> 16;
    int p = t & 65535;
    const float* src = dd + (size_t)(2 * b + 1) * 128 * 65536 + p;
    float ss = 0.f;
    size_t ob = (size_t)t * 128;
#pragma unroll 4
    for (int c8 = 0; c8 < 16; ++c8) {
        v8u h8, l8;
#pragma unroll
        for (int j = 0; j < 8; ++j) {
            float x = src[(size_t)(c8 * 8 + j) * 65536];
            ss += x * x;
            unsigned short h = f2bf(x);
            h8[j] = h;
            l8[j] = f2bf(x - bf2f(h));
        }
        *(v8u*)(Bhi + ob + c8 * 8) = h8;
        *(v8u*)(Blo + ob + c8 * 8) = l8;
    }
    invx[t] = 1.0f / fmaxf(sqrtf(ss), 1e-12f);
}

// ---------------- fused GEMM (128x128 tile, K_ext=384, LDS staged) ----------
// MODE 0: per-(row, mtile) partials {sum e, sum e*m_local}
// MODE 1: write p = e * invS[row] to soft_match_vals
// grid (512 mt, 4 ny, 4 b), 256 threads = 4 waves (wm = w&1 m-half, wn = w>>1
// n-half); s = acc*invx[m]; e = exp2((s-1)*144.27)
template <int MODE>
__global__ void __launch_bounds__(256, 2) k_gemm(const unsigned short* __restrict__ Ahi,
                                                 const unsigned short* __restrict__ Alo,
                                                 const unsigned short* __restrict__ Bhi,
                                                 const unsigned short* __restrict__ Blo,
                                                 const float* __restrict__ invx,
                                                 const float4* __restrict__ rows,
                                                 float2* __restrict__ part,
                                                 float* __restrict__ osm) {
    __shared__ v4f ldsbuf[4096];           // 64 KB: 2 x (Kp 16K + Px 16K); aliased by epilogues
    __shared__ float ldsInv[128];
    char* lds = (char*)ldsbuf;

    const int tid = threadIdx.x;
    const int l = tid & 63, w = tid >> 6;
    const int wm = w & 1, wn = w >> 1;
    const int l15 = l & 15, l16 = l >> 4;
    const int mt = blockIdx.x, ny = blockIdx.y, b = blockIdx.z;

    const size_t kprow0 = (size_t)(b * 512 + ny * 128) * 128;   // Ahi/Alo elem offset
    const size_t pxrow0 = (size_t)(b * 65536 + mt * 128) * 128; // Bhi/Blo elem offset

    if (tid < 128) ldsInv[tid] = invx[b * 65536 + mt * 128 + tid];

    // staging slots: 1024 granules (16B) per matrix tile, 4 per thread
    int soff[4], sdst[4];
#pragma unroll
    for (int i = 0; i < 4; ++i) {
        int s = tid + i * 256;
        int rl = s >> 3, g = s & 7;
        soff[i] = rl * 128 + ((g ^ (rl & 7)) << 3);   // pre-swizzled global elem offset
        sdst[i] = s << 4;                             // linear LDS byte offset
    }

    v4f acc[4][4];
#pragma unroll
    for (int mf = 0; mf < 4; ++mf)
#pragma unroll
        for (int nf = 0; nf < 4; ++nf) { v4f z = {0.f, 0.f, 0.f, 0.f}; acc[mf][nf] = z; }

    // K-step kb: term t=kb>>1 -> {Ah*Bh, Ah*Bl, Al*Bh}; k_off=(kb&1)*64
#define STAGE(kb, buf)                                                              \
    {                                                                               \
        const unsigned short* kp = (((kb) < 4) ? Ahi : Alo) + kprow0 + (((kb) & 1) << 6); \
        const unsigned short* px = ((((kb) >> 1) == 1) ? Blo : Bhi) + pxrow0 + (((kb) & 1) << 6); \
        char* base = lds + (buf) * 32768;                                           \
        _Pragma("unroll")                                                           \
        for (int i = 0; i < 4; ++i) {                                               \
            gl_lds16(kp + soff[i], base + sdst[i]);                                 \
            gl_lds16(px + soff[i], base + 16384 + sdst[i]);                         \
        }                                                                           \
    }

    STAGE(0, 0);
    int buf = 0;
#pragma unroll
    for (int kb = 0; kb < 6; ++kb) {
        if (kb < 5) STAGE(kb + 1, buf ^ 1);
        // Counted wait: keep this iter's 8 staging loads in flight, drain only
        // the previous tile's. Last iter has no new stage -> drain to 0.
        if (kb == 0)      asm volatile("s_waitcnt vmcnt(8) lgkmcnt(0)" ::: "memory");
        else if (kb < 5)  asm volatile("s_waitcnt vmcnt(8)" ::: "memory");
        else              asm volatile("s_waitcnt vmcnt(0)" ::: "memory");
        __builtin_amdgcn_s_barrier();
        __builtin_amdgcn_sched_barrier(0);   // keep ds_reads below the barrier
        const char* kp = lds + buf * 32768;
        const char* px = kp + 16384;
#pragma unroll
        for (int ks = 0; ks < 2; ++ks) {
            v8s af[4], bf[4];
#pragma unroll
            for (int mf = 0; mf < 4; ++mf) {
                int r = wm * 64 + mf * 16 + l15;
                int g = ((ks << 2) | l16) ^ (r & 7);
                af[mf] = *(const v8s*)(px + r * 128 + (g << 4));
            }
#pragma unroll
            for (int nf = 0; nf < 4; ++nf) {
                int r = wn * 64 + nf * 16 + l15;
                int g = ((ks << 2) | l16) ^ (r & 7);
                bf[nf] = *(const v8s*)(kp + r * 128 + (g << 4));
            }
#pragma unroll
            for (int mf = 0; mf < 4; ++mf)
#pragma unroll
                for (int nf = 0; nf < 4; ++nf)
                    acc[mf][nf] = __builtin_amdgcn_mfma_f32_16x16x32_bf16(af[mf], bf[nf], acc[mf][nf], 0, 0, 0);
        }
        __builtin_amdgcn_sched_barrier(0);   // keep reads/MFMA above barrier B
        __builtin_amdgcn_s_barrier();        // raw: no vmcnt drain
        buf ^= 1;
    }
#undef STAGE
    // output frag: row = m = wm*64+mf*16+l16*4+r; col = n = wn*64+nf*16+l15

    if (MODE == 0) {
        float sS[4], sM[4];
#pragma unroll
        for (int nf = 0; nf < 4; ++nf) { sS[nf] = 0.f; sM[nf] = 0.f; }
#pragma unroll
        for (int mf = 0; mf < 4; ++mf) {
            int mloc = wm * 64 + mf * 16 + l16 * 4;
#pragma unroll
            for (int nf = 0; nf < 4; ++nf)
#pragma unroll
                for (int r = 0; r < 4; ++r) {
                    float sv = acc[mf][nf][r] * ldsInv[mloc + r];
                    float e = __builtin_amdgcn_exp2f(fmaf(sv, EXP2_SCALE, -EXP2_SCALE));
                    sS[nf] += e;
                    sM[nf] = fmaf(e, (float)(mloc + r), sM[nf]);
                }
        }
#pragma unroll
        for (int nf = 0; nf < 4; ++nf) {   // reduce across l16 groups (m)
            sS[nf] += __shfl_xor(sS[nf], 16, 64); sS[nf] += __shfl_xor(sS[nf], 32, 64);
            sM[nf] += __shfl_xor(sM[nf], 16, 64); sM[nf] += __shfl_xor(sM[nf], 32, 64);
        }
        float* red = (float*)lds;          // [4 w][4 nf][16 l15][2]
        if (l < 16) {
#pragma unroll
            for (int nf = 0; nf < 4; ++nf) {
                red[((w * 4 + nf) * 16 + l15) * 2 + 0] = sS[nf];
                red[((w * 4 + nf) * 16 + l15) * 2 + 1] = sM[nf];
            }
        }
        __syncthreads();
        // combine wm halves: 256 thr = wn(2) x nf(4) x l15(16) x q(2)
        int q = tid & 1, p15 = (tid >> 1) & 15, pnf = (tid >> 5) & 3, pwn = tid >> 7;
        float vs = red[(((pwn * 2 + 0) * 4 + pnf) * 16 + p15) * 2 + q]
                 + red[(((pwn * 2 + 1) * 4 + pnf) * 16 + p15) * 2 + q];
        int rowg = b * 512 + ny * 128 + pwn * 64 + pnf * 16 + p15;
        ((float*)part)[((size_t)rowg * 512 + mt) * 2 + q] = vs;
    } else {
        float invs[4];
#pragma unroll
        for (int nf = 0; nf < 4; ++nf)
            invs[nf] = rows[b * 512 + ny * 128 + wn * 64 + nf * 16 + l15].x;
        // write p tile into LDS [128 n][128 m] f32, granule-swizzled
#pragma unroll
        for (int mf = 0; mf < 4; ++mf) {
            int mloc = wm * 64 + mf * 16 + l16 * 4;
#pragma unroll
            for (int nf = 0; nf < 4; ++nf) {
                int nloc = wn * 64 + nf * 16 + l15;
                v4f pv;
#pragma unroll
                for (int r = 0; r < 4; ++r) {
                    float sv = acc[mf][nf][r] * ldsInv[mloc + r];
                    pv[r] = __builtin_amdgcn_exp2f(fmaf(sv, EXP2_SCALE, -EXP2_SCALE)) * invs[nf];
                }
                int g = (mloc >> 2) ^ (nloc & 7);
                *(v4f*)(lds + nloc * 512 + (g << 4)) = pv;
            }
        }
        __syncthreads();
        // cooperative store: 512B contiguous per row, nontemporal (protect L3)
        size_t obase = (size_t)(b * 512 + ny * 128) * 65536 + (size_t)mt * 128;
        int g = tid & 31, rh = tid >> 5;   // rh 0..7
#pragma unroll
        for (int it = 0; it < 16; ++it) {
            int r = it * 8 + rh;
            v4f v = *(const v4f*)(lds + r * 512 + ((g ^ (r & 7)) << 4));
            __builtin_nontemporal_store(v, (v4f*)(osm + obase + (size_t)r * 65536 + (g << 2)));
        }
    }
}

// ---------------- reduce partials -> rowstats{invS,u,v}; write pseudo_coords ----
__global__ void __launch_bounds__(256) k_reduce(const float2* __restrict__ part,
                                                float4* __restrict__ rows,
                                                float* __restrict__ out) {
    int r = blockIdx.x * 4 + (threadIdx.x >> 6);  // 0..2047
    int l = threadIdx.x & 63;
    float S = 0.f, Su = 0.f, Sv = 0.f;
#pragma unroll
    for (int i = 0; i < 8; ++i) {
        int mtv = l + i * 64;
        float2 p = part[(size_t)r * 512 + mtv];
        S += p.x;
        Su += (float)((mtv & 1) * 128) * p.x + p.y;
        Sv += (float)(mtv >> 1) * p.x;
    }
#pragma unroll
    for (int m = 1; m < 64; m <<= 1) {
        S += __shfl_xor(S, m, 64);
        Su += __shfl_xor(Su, m, 64);
        Sv += __shfl_xor(Sv, m, 64);
    }
    if (l == 0) {
        float invS = 1.0f / S;
        float u = Su * invS, v = Sv * invS;
        rows[r] = make_float4(invS, u, v, 0.f);
        out[r * 2] = u;
        out[r * 2 + 1] = v;
    }
}

// ---------------- bilinear sample + match weights ----
__global__ void __launch_bounds__(256) k_sample(const float* __restrict__ ksc,
                                                const float* __restrict__ sd,
                                                const float* __restrict__ dd,
                                                const float* __restrict__ srcN,
                                                const float4* __restrict__ rows,
                                                float* __restrict__ out) {
    int gw = blockIdx.x * 4 + (threadIdx.x >> 6);  // b*512+n
    int l = threadIdx.x & 63;
    int b = gw >> 9, n = gw & 511;
    float4 rs = rows[gw];
    float u = rs.y, v = rs.z;
    float un = 2.0f * u / 255.0f - 1.0f;
    float vn = 2.0f * v / 255.0f - 1.0f;
    float x = ((un + 1.0f) * 256.0f - 1.0f) * 0.5f;
    float y = ((vn + 1.0f) * 256.0f - 1.0f) * 0.5f;
    float x0f = floorf(x), y0f = floorf(y);
    int x0 = (int)x0f, y0 = (int)y0f;
    int x1 = x0 + 1, y1 = y0 + 1;
    float wx1 = x - x0f, wy1 = y - y0f;
    float wx0 = 1.0f - wx1, wy0 = 1.0f - wy1;
    float m00 = ((x0 >= 0) & (x0 <= 255) & (y0 >= 0) & (y0 <= 255)) ? 1.f : 0.f;
    float m10 = ((x1 >= 0) & (x1 <= 255) & (y0 >= 0) & (y0 <= 255)) ? 1.f : 0.f;
    float m01 = ((x0 >= 0) & (x0 <= 255) & (y1 >= 0) & (y1 <= 255)) ? 1.f : 0.f;
    float m11 = ((x1 >= 0) & (x1 <= 255) & (y1 >= 0) & (y1 <= 255)) ? 1.f : 0.f;
    int cx0 = min(max(x0, 0), 255), cx1 = min(max(x1, 0), 255);
    int cy0 = min(max(y0, 0), 255), cy1 = min(max(y1, 0), 255);
    int i00 = cy0 * 256 + cx0, i10 = cy0 * 256 + cx1;
    int i01 = cy1 * 256 + cx0, i11 = cy1 * 256 + cx1;
    float w00 = wx0 * wy0 * m00, w10 = wx1 * wy0 * m10;
    float w01 = wx0 * wy1 * m01, w11 = wx1 * wy1 * m11;

    const float* sdb = sd + (size_t)(2 * b + 1) * 65536;
    float ps = w00 * sdb[i00] + w10 * sdb[i10] + w01 * sdb[i01] + w11 * sdb[i11];

    const float* ddb = dd + (size_t)(2 * b + 1) * 128 * 65536;
    float dot = 0.f;
#pragma unroll
    for (int h = 0; h < 2; ++h) {
        int c = l + h * 64;
        const float* dc = ddb + (size_t)c * 65536;
        float pd = w00 * dc[i00] + w10 * dc[i10] + w01 * dc[i01] + w11 * dc[i11];
        dot += srcN[gw * 128 + c] * pd;
    }
#pragma unroll
    for (int m = 1; m < 64; m <<= 1) dot += __shfl_xor(dot, m, 64);
    if (l == 0) {
        float dms = dot / 128.0f;
        float sscore = ksc[(2 * b) * 512 + n];
        out[4096 + gw] = 0.5f * (dms + 1.0f) * sscore * ps;
    }
}

extern "C" void kernel_launch(void* const* d_in, const int* in_sizes, int n_in,
                              void* d_out, int out_size, void* d_ws, size_t ws_size,
                              hipStream_t stream) {
    const float* ksc = (const float*)d_in[0];  // (8,1,512)
    const float* kd  = (const float*)d_in[1];  // (8,128,512)
    const float* sd  = (const float*)d_in[2];  // (8,1,256,256)
    const float* dd  = (const float*)d_in[3];  // (8,128,256,256)
    float* out = (float*)d_out;                // coords(4096) | mw(2048) | sm(134217728)
    char* ws = (char*)d_ws;

    unsigned short* Ahi  = (unsigned short*)(ws + O_AHI);
    unsigned short* Alo  = (unsigned short*)(ws + O_ALO);
    float*          srcN = (float*)(ws + O_SRCN);
    unsigned short* Bhi  = (unsigned short*)(ws + O_BHI);
    unsigned short* Blo  = (unsigned short*)(ws + O_BLO);
    float2*         part = (float2*)(ws + O_PART);
    float4*         rows = (float4*)(ws + O_ROWS);
    float*          invx = (float*)(ws + O_INVX);
    float*          osm  = out + 6144;

    k_prep_src<<<512, 256, 0, stream>>>(kd, srcN, Ahi, Alo);
    k_prep_tgt<<<1024, 256, 0, stream>>>(dd, Bhi, Blo, invx);
    k_gemm<0><<<dim3(512, 4, 4), 256, 0, stream>>>(Ahi, Alo, Bhi, Blo, invx, rows, part, osm);
    k_reduce<<<512, 256, 0, stream>>>(part, rows, out);
    k_gemm<1><<<dim3(512, 4, 4), 256, 0, stream>>>(Ahi, Alo, Bhi, Blo, invx, rows, part, osm);
    k_sample<<<512, 256, 0, stream>>>(ksc, sd, dd, srcN, rows, out);
}

// Round 5
// 418.300 us; speedup vs baseline: 1.1853x; 1.1349x over previous
//
#include <hip/hip_runtime.h>

// SoftmaxMatcher on MI355X — round 5.
//  * A (keypoint descs, hi+lo) held in VGPRs per wave (loaded once per block
//    from L2) -> LDS stages ONLY the pixel matrix: 8 ds_read_b128 per 64 MFMA.
//  * Term-grouped K-steps: [Bh0:(Ah0+Al0), Bh1:(Ah1+Al1), Bl0:Ah0, Bl1:Ah1]
//    -> B staged once per half, 4 steps/tile instead of 6.
//  * MT_PER=16 px-tiles per block, grid 512 = 2 blocks/CU all-resident;
//    continuous double-buffered staging with exact counted vmcnt across
//    tile boundaries (4 steady / 20|5 post-epilogue / 0 tail).
//  * pass_b epilogue: dedicated 32KB LDS chunk, 2 rounds (n-halves), 512B-row
//    nontemporal stores streamed between next tile's K-steps.

typedef short  v8s __attribute__((ext_vector_type(8)));
typedef unsigned short v8u __attribute__((ext_vector_type(8)));
typedef float  v4f __attribute__((ext_vector_type(4)));

#define EXP2_SCALE 144.269504088896f   // 1/(0.01*ln2)
#define WAITV(N) asm volatile("s_waitcnt vmcnt(" #N ")" ::: "memory")

// ---- workspace layout (bytes) ----
static const size_t O_AHI  = 0;                        // ushort[2048*128]
static const size_t O_ALO  = O_AHI  + 262144ull*2;
static const size_t O_SRCN = O_ALO  + 262144ull*2;     // float[2048*128]
static const size_t O_BHI  = O_SRCN + 262144ull*4;     // ushort[262144*128] 64MB
static const size_t O_BLO  = O_BHI  + 33554432ull*2;   // 64MB
static const size_t O_PART = O_BLO  + 33554432ull*2;   // float[2048*512*2]  8MB
static const size_t O_ROWS = O_PART + 2048ull*512*8;   // float4[2048]

static __device__ inline unsigned short f2bf(float x) {
    unsigned u = __float_as_uint(x);
    u = u + 0x7FFFu + ((u >> 16) & 1u);   // RNE
    return (unsigned short)(u >> 16);
}
static __device__ inline float bf2f(unsigned short h) {
    return __uint_as_float(((unsigned)h) << 16);
}

__device__ __forceinline__ void gl_lds16(const void* g, void* l) {
    auto gp = (const __attribute__((address_space(1))) unsigned int*)(uintptr_t)g;
    auto lp = (__attribute__((address_space(3))) unsigned int*)(uintptr_t)l;
    __builtin_amdgcn_global_load_lds(gp, lp, 16, 0, 0);
}

// ---------------- prep: normalize src keypoint descs, bf16 hi/lo, [row][k] ----
__global__ void __launch_bounds__(256) k_prep_src(const float* __restrict__ kd,
                                                  float* __restrict__ srcN,
                                                  unsigned short* __restrict__ Ahi,
                                                  unsigned short* __restrict__ Alo) {
    int gw = blockIdx.x * 4 + (threadIdx.x >> 6);  // 0..2047 = b*512+n
    int l  = threadIdx.x & 63;
    int b  = gw >> 9, n = gw & 511;
    const float* base = kd + (size_t)(2 * b) * 128 * 512;
    float x0 = base[l * 512 + n];
    float x1 = base[(l + 64) * 512 + n];
    float ss = x0 * x0 + x1 * x1;
#pragma unroll
    for (int m = 1; m < 64; m <<= 1) ss += __shfl_xor(ss, m, 64);
    float inv = 1.0f / fmaxf(sqrtf(ss), 1e-12f);
    float xn0 = x0 * inv, xn1 = x1 * inv;
    int ob = gw * 128;
    srcN[ob + l] = xn0;  srcN[ob + l + 64] = xn1;
    unsigned short h0 = f2bf(xn0), h1 = f2bf(xn1);
    Ahi[ob + l] = h0;        Ahi[ob + l + 64] = h1;
    Alo[ob + l] = f2bf(xn0 - bf2f(h0));
    Alo[ob + l + 64] = f2bf(xn1 - bf2f(h1));
}

// ---------------- prep: normalize tgt dense descs, transpose to [m][k], hi/lo ----
__global__ void __launch_bounds__(256, 2) k_prep_tgt(const float* __restrict__ dd,
                                                     unsigned short* __restrict__ Bhi,
                                                     unsigned short* __restrict__ Blo) {
    int t = blockIdx.x * 256 + threadIdx.x;   // 0..262143
    int b = t >> 16;
    int p = t & 65535;
    const float* src = dd + (size_t)(2 * b + 1) * 128 * 65536 + p;
    float v[128];
    float ss = 0.f;
#pragma unroll
    for (int c = 0; c < 128; ++c) { float x = src[(size_t)c * 65536]; v[c] = x; ss += x * x; }
    float inv = 1.0f / fmaxf(sqrtf(ss), 1e-12f);
    size_t ob = (size_t)t * 128;
#pragma unroll
    for (int c8 = 0; c8 < 16; ++c8) {
        v8u h8, l8;
#pragma unroll
        for (int j = 0; j < 8; ++j) {
            float xn = v[c8 * 8 + j] * inv;
            unsigned short h = f2bf(xn);
            h8[j] = h;
            l8[j] = f2bf(xn - bf2f(h));
        }
        *(v8u*)(Bhi + ob + c8 * 8) = h8;
        *(v8u*)(Blo + ob + c8 * 8) = l8;
    }
}

// ---------------- fused GEMM, A-in-VGPR, 16 tiles/block --------------------
// grid (32 mtg, 4 ny, 4 b) = 512 blocks, 256 thr = 4 waves (wm=w&1, wn=w>>1).
// MODE 0: per-(row, mt) partials {sum e, sum e*m_local} -> part
// MODE 1: p = e * invS[row] -> osm
template <int MODE>
__global__ void __launch_bounds__(256, 2) k_gemm(const unsigned short* __restrict__ Ahi,
                                                 const unsigned short* __restrict__ Alo,
                                                 const unsigned short* __restrict__ Bhi,
                                                 const unsigned short* __restrict__ Blo,
                                                 const float4* __restrict__ rows,
                                                 float* __restrict__ part,
                                                 float* __restrict__ osm) {
    __shared__ v4f bstage4[2048];                        // 32 KB: 2 x 16KB B halves
    __shared__ float paux[MODE == 1 ? 8192 : 512];       // 32 KB ptile chunk | 2KB red
    char* bstage = (char*)bstage4;

    const int tid = threadIdx.x;
    const int l = tid & 63, w = tid >> 6;
    const int wm = w & 1, wn = w >> 1;
    const int l15 = l & 15, l16 = l >> 4;
    const int mtg = blockIdx.x, ny = blockIdx.y, b = blockIdx.z;
    const int mt0 = mtg * 16;

    // ---- A fragments in VGPRs: [nf][ksl(32-wide k-slice)] for hi and lo ----
    v8s ahi[4][4], alo[4][4];
    {
        const size_t ar = ((size_t)(b * 512 + ny * 128 + wn * 64 + l15)) * 128 + l16 * 8;
#pragma unroll
        for (int nf = 0; nf < 4; ++nf)
#pragma unroll
            for (int ksl = 0; ksl < 4; ++ksl) {
                ahi[nf][ksl] = *(const v8s*)(Ahi + ar + nf * 2048 + ksl * 32);
                alo[nf][ksl] = *(const v8s*)(Alo + ar + nf * 2048 + ksl * 32);
            }
    }
    float invs[4];
    if (MODE == 1) {
#pragma unroll
        for (int nf = 0; nf < 4; ++nf)
            invs[nf] = rows[b * 512 + ny * 128 + wn * 64 + nf * 16 + l15].x;
    }
    asm volatile("s_waitcnt vmcnt(0)" ::: "memory");   // A regs ready; clean vm FIFO

    size_t pxrow = ((size_t)b * 65536 + (size_t)mt0 * 128) * 128;

    // stage step s (0..3) of tile at prow into buffer buf:
    // s0: Bhi k0-63, s1: Bhi k64-127, s2: Blo k0-63, s3: Blo k64-127
#define STAGE(s, buf, prow)                                                         \
    {                                                                               \
        const unsigned short* src = (((s) < 2) ? Bhi : Blo) + (prow) + (((s) & 1) << 6); \
        char* dst = bstage + (buf) * 16384;                                         \
        _Pragma("unroll")                                                           \
        for (int i = 0; i < 4; ++i) {                                               \
            int sl = tid + i * 256;                                                 \
            int rl = sl >> 3, gg = sl & 7;                                          \
            gl_lds16(src + rl * 128 + ((gg ^ (rl & 7)) << 3), dst + (sl << 4));     \
        }                                                                           \
    }

    STAGE(0, 0, pxrow);

    for (int mt = 0; mt < 16; ++mt) {
        v4f acc[4][4];
#pragma unroll
        for (int mf = 0; mf < 4; ++mf)
#pragma unroll
            for (int nf = 0; nf < 4; ++nf) { v4f z = {0.f, 0.f, 0.f, 0.f}; acc[mf][nf] = z; }

#pragma unroll
        for (int s = 0; s < 4; ++s) {
            if (s < 3)            STAGE(s + 1, (s + 1) & 1, pxrow)
            else if (mt < 15)     STAGE(0, 0, pxrow + 16384)

            // counted waits (vm FIFO: [4 this-step][E epilogue stores][4 next])
            if (s == 0) {
                if (mt == 0) WAITV(4);
                else if (MODE == 1) WAITV(20);
                else WAITV(5);
            } else if (s == 3 && mt == 15) {
                WAITV(0);
            } else {
                WAITV(4);
            }
            __builtin_amdgcn_s_barrier();
            __builtin_amdgcn_sched_barrier(0);

            const char* bb = bstage + (s & 1) * 16384;
#pragma unroll
            for (int k2 = 0; k2 < 2; ++k2) {
                const int ksl = ((s & 1) << 1) | k2;
                v8s pxf[4];
#pragma unroll
                for (int mf = 0; mf < 4; ++mf) {
                    int r = wm * 64 + mf * 16 + l15;
                    pxf[mf] = *(const v8s*)(bb + r * 128 + ((((k2 << 2) | l16) ^ (r & 7)) << 4));
                }
#pragma unroll
                for (int mf = 0; mf < 4; ++mf)
#pragma unroll
                    for (int nf = 0; nf < 4; ++nf) {
                        acc[mf][nf] = __builtin_amdgcn_mfma_f32_16x16x32_bf16(pxf[mf], ahi[nf][ksl], acc[mf][nf], 0, 0, 0);
                        if (s < 2)
                            acc[mf][nf] = __builtin_amdgcn_mfma_f32_16x16x32_bf16(pxf[mf], alo[nf][ksl], acc[mf][nf], 0, 0, 0);
                    }
            }
            __builtin_amdgcn_sched_barrier(0);
            __builtin_amdgcn_s_barrier();
        }

        // ---- per-tile epilogue (raw barriers; no vmcnt drain) ----
        if (MODE == 0) {
            float sS[4], sM[4];
#pragma unroll
            for (int nf = 0; nf < 4; ++nf) { sS[nf] = 0.f; sM[nf] = 0.f; }
#pragma unroll
            for (int mf = 0; mf < 4; ++mf) {
                int mloc = wm * 64 + mf * 16 + l16 * 4;
#pragma unroll
                for (int nf = 0; nf < 4; ++nf)
#pragma unroll
                    for (int r = 0; r < 4; ++r) {
                        float e = __builtin_amdgcn_exp2f(fmaf(acc[mf][nf][r], EXP2_SCALE, -EXP2_SCALE));
                        sS[nf] += e;
                        sM[nf] = fmaf(e, (float)(mloc + r), sM[nf]);
                    }
            }
#pragma unroll
            for (int nf = 0; nf < 4; ++nf) {
                sS[nf] += __shfl_xor(sS[nf], 16, 64); sS[nf] += __shfl_xor(sS[nf], 32, 64);
                sM[nf] += __shfl_xor(sM[nf], 16, 64); sM[nf] += __shfl_xor(sM[nf], 32, 64);
            }
            if (l < 16) {
#pragma unroll
                for (int nf = 0; nf < 4; ++nf) {
                    paux[((w * 4 + nf) * 16 + l15) * 2 + 0] = sS[nf];
                    paux[((w * 4 + nf) * 16 + l15) * 2 + 1] = sM[nf];
                }
            }
            asm volatile("s_waitcnt lgkmcnt(0)" ::: "memory");
            __builtin_amdgcn_s_barrier();
            int q = tid & 1, p15 = (tid >> 1) & 15, pnf = (tid >> 5) & 3, pwn = tid >> 7;
            float vs = paux[(((pwn * 2 + 0) * 4 + pnf) * 16 + p15) * 2 + q]
                     + paux[(((pwn * 2 + 1) * 4 + pnf) * 16 + p15) * 2 + q];
            int rowg = b * 512 + ny * 128 + pwn * 64 + pnf * 16 + p15;
            part[((size_t)rowg * 512 + (mt0 + mt)) * 2 + q] = vs;   // 1 store (E=1)
        } else {
            const size_t ocol = (size_t)(mt0 + mt) * 128;
            const int g = tid & 31, rh = tid >> 5;
#pragma unroll
            for (int half = 0; half < 2; ++half) {
                if (wn == half) {
#pragma unroll
                    for (int mf = 0; mf < 4; ++mf) {
                        int mq = wm * 16 + mf * 4 + l16;   // granule index m>>2
#pragma unroll
                        for (int nf = 0; nf < 4; ++nf) {
                            int nl = nf * 16 + l15;
                            v4f pv;
#pragma unroll
                            for (int r = 0; r < 4; ++r)
                                pv[r] = __builtin_amdgcn_exp2f(fmaf(acc[mf][nf][r], EXP2_SCALE, -EXP2_SCALE)) * invs[nf];
                            *(v4f*)((char*)paux + nl * 512 + ((mq ^ (nl & 7)) << 4)) = pv;
                        }
                    }
                }
                asm volatile("s_waitcnt lgkmcnt(0)" ::: "memory");
                __builtin_amdgcn_s_barrier();
                size_t orow = (size_t)(b * 512 + ny * 128 + half * 64);
#pragma unroll
                for (int it = 0; it < 8; ++it) {
                    int r = it * 8 + rh;
                    v4f v = *(const v4f*)((const char*)paux + r * 512 + ((g ^ (r & 7)) << 4));
                    __builtin_nontemporal_store(v, (v4f*)(osm + (orow + r) * 65536 + ocol + g * 4));
                }
                __builtin_amdgcn_s_barrier();
            }
            // E = 16 stores outstanding
        }
        pxrow += 16384;
    }
#undef STAGE
}

// ---------------- reduce partials -> rowstats{invS,u,v}; write pseudo_coords ----
__global__ void __launch_bounds__(256) k_reduce(const float2* __restrict__ part,
                                                float4* __restrict__ rows,
                                                float* __restrict__ out) {
    int r = blockIdx.x * 4 + (threadIdx.x >> 6);  // 0..2047
    int l = threadIdx.x & 63;
    float S = 0.f, Su = 0.f, Sv = 0.f;
#pragma unroll
    for (int i = 0; i < 8; ++i) {
        int mtv = l + i * 64;
        float2 p = part[(size_t)r * 512 + mtv];
        S += p.x;
        Su += (float)((mtv & 1) * 128) * p.x + p.y;
        Sv += (float)(mtv >> 1) * p.x;
    }
#pragma unroll
    for (int m = 1; m < 64; m <<= 1) {
        S += __shfl_xor(S, m, 64);
        Su += __shfl_xor(Su, m, 64);
        Sv += __shfl_xor(Sv, m, 64);
    }
    if (l == 0) {
        float invS = 1.0f / S;
        float u = Su * invS, v = Sv * invS;
        rows[r] = make_float4(invS, u, v, 0.f);
        out[r * 2] = u;
        out[r * 2 + 1] = v;
    }
}

// ---------------- bilinear sample + match weights ----
__global__ void __launch_bounds__(256) k_sample(const float* __restrict__ ksc,
                                                const float* __restrict__ sd,
                                                const float* __restrict__ dd,
                                                const float* __restrict__ srcN,
                                                const float4* __restrict__ rows,
                                                float* __restrict__ out) {
    int gw = blockIdx.x * 4 + (threadIdx.x >> 6);  // b*512+n
    int l = threadIdx.x & 63;
    int b = gw >> 9, n = gw & 511;
    float4 rs = rows[gw];
    float u = rs.y, v = rs.z;
    float un = 2.0f * u / 255.0f - 1.0f;
    float vn = 2.0f * v / 255.0f - 1.0f;
    float x = ((un + 1.0f) * 256.0f - 1.0f) * 0.5f;
    float y = ((vn + 1.0f) * 256.0f - 1.0f) * 0.5f;
    float x0f = floorf(x), y0f = floorf(y);
    int x0 = (int)x0f, y0 = (int)y0f;
    int x1 = x0 + 1, y1 = y0 + 1;
    float wx1 = x - x0f, wy1 = y - y0f;
    float wx0 = 1.0f - wx1, wy0 = 1.0f - wy1;
    float m00 = ((x0 >= 0) & (x0 <= 255) & (y0 >= 0) & (y0 <= 255)) ? 1.f : 0.f;
    float m10 = ((x1 >= 0) & (x1 <= 255) & (y0 >= 0) & (y0 <= 255)) ? 1.f : 0.f;
    float m01 = ((x0 >= 0) & (x0 <= 255) & (y1 >= 0) & (y1 <= 255)) ? 1.f : 0.f;
    float m11 = ((x1 >= 0) & (x1 <= 255) & (y1 >= 0) & (y1 <= 255)) ? 1.f : 0.f;
    int cx0 = min(max(x0, 0), 255), cx1 = min(max(x1, 0), 255);
    int cy0 = min(max(y0, 0), 255), cy1 = min(max(y1, 0), 255);
    int i00 = cy0 * 256 + cx0, i10 = cy0 * 256 + cx1;
    int i01 = cy1 * 256 + cx0, i11 = cy1 * 256 + cx1;
    float w00 = wx0 * wy0 * m00, w10 = wx1 * wy0 * m10;
    float w01 = wx0 * wy1 * m01, w11 = wx1 * wy1 * m11;

    const float* sdb = sd + (size_t)(2 * b + 1) * 65536;
    float ps = w00 * sdb[i00] + w10 * sdb[i10] + w01 * sdb[i01] + w11 * sdb[i11];

    const float* ddb = dd + (size_t)(2 * b + 1) * 128 * 65536;
    float dot = 0.f;
#pragma unroll
    for (int h = 0; h < 2; ++h) {
        int c = l + h * 64;
        const float* dc = ddb + (size_t)c * 65536;
        float pd = w00 * dc[i00] + w10 * dc[i10] + w01 * dc[i01] + w11 * dc[i11];
        dot += srcN[gw * 128 + c] * pd;
    }
#pragma unroll
    for (int m = 1; m < 64; m <<= 1) dot += __shfl_xor(dot, m, 64);
    if (l == 0) {
        float dms = dot / 128.0f;
        float sscore = ksc[(2 * b) * 512 + n];
        out[4096 + gw] = 0.5f * (dms + 1.0f) * sscore * ps;
    }
}

extern "C" void kernel_launch(void* const* d_in, const int* in_sizes, int n_in,
                              void* d_out, int out_size, void* d_ws, size_t ws_size,
                              hipStream_t stream) {
    const float* ksc = (const float*)d_in[0];  // (8,1,512)
    const float* kd  = (const float*)d_in[1];  // (8,128,512)
    const float* sd  = (const float*)d_in[2];  // (8,1,256,256)
    const float* dd  = (const float*)d_in[3];  // (8,128,256,256)
    float* out = (float*)d_out;                // coords(4096) | mw(2048) | sm(134217728)
    char* ws = (char*)d_ws;

    unsigned short* Ahi  = (unsigned short*)(ws + O_AHI);
    unsigned short* Alo  = (unsigned short*)(ws + O_ALO);
    float*          srcN = (float*)(ws + O_SRCN);
    unsigned short* Bhi  = (unsigned short*)(ws + O_BHI);
    unsigned short* Blo  = (unsigned short*)(ws + O_BLO);
    float*          part = (float*)(ws + O_PART);
    float4*         rows = (float4*)(ws + O_ROWS);
    float*          osm  = out + 6144;

    k_prep_src<<<512, 256, 0, stream>>>(kd, srcN, Ahi, Alo);
    k_prep_tgt<<<1024, 256, 0, stream>>>(dd, Bhi, Blo);
    k_gemm<0><<<dim3(32, 4, 4), 256, 0, stream>>>(Ahi, Alo, Bhi, Blo, rows, part, osm);
    k_reduce<<<512, 256, 0, stream>>>((const float2*)part, rows, out);
    k_gemm<1><<<dim3(32, 4, 4), 256, 0, stream>>>(Ahi, Alo, Bhi, Blo, rows, part, osm);
    k_sample<<<512, 256, 0, stream>>>(ksc, sd, dd, srcN, rows, out);
}